// Round 5
// baseline (149.317 us; speedup 1.0000x reference)
//
#include <hip/hip_runtime.h>

#define HW    262144      // 512*512
#define BNUM  4
#define NC    33          // labels 0..32
#define NI    32          // instance channels

#define NB     2048       // t-space bins
#define BSCALE 128.0f     // NB / TMAX (TMAX = 16)
#define EG     8192       // e-grid bins in scan
#define ESCALE 4096.0f    // EG / 2.0

typedef unsigned long long ull;

// word (float/u32) offsets within each sample's workspace slice
#define W_TH   0                    // u64[NB] packed (pos<<32)|neg -> 4096 words
#define W_E0   4096
#define W_E1   (W_E0 + NC)          // 4129
#define W_SS   (W_E1 + NC)          // 4162
#define W_SS2  (W_SS + NC)          // 4195
#define W_CNT  (W_SS2 + NC)         // 4228
#define W_LOSS (W_CNT + NC)         // 4261
#define W_STRIDE 4272               // 16B-aligned stride

// ---------------- Pass A: per-instance stats, per-wave privatized, 4 px/thread
__global__ void __launch_bounds__(256) stats_kernel(
    const float* __restrict__ emb, const float* __restrict__ sig,
    const int* __restrict__ gt, float* __restrict__ ws) {
  int s = blockIdx.y;
  float* wsS = ws + (size_t)s * W_STRIDE;
  __shared__ float a0[4][NC], a1[4][NC], as_[4][NC], as2[4][NC];
  __shared__ unsigned ac[4][NC];
  int t = threadIdx.x;
  int w = t >> 6;
  for (int k = t; k < 4 * NC; k += 256) {
    ((float*)a0)[k] = 0.f; ((float*)a1)[k] = 0.f;
    ((float*)as_)[k] = 0.f; ((float*)as2)[k] = 0.f;
    ((unsigned*)ac)[k] = 0u;
  }
  __syncthreads();
  const float* e0p = emb + (size_t)s * 2 * HW;
  const float* e1p = e0p + HW;
  const float* sp  = sig + (size_t)s * HW;
  const int*   gp  = gt  + (size_t)s * HW;
  int idx = blockIdx.x * 1024 + t * 4;
  int4   lb = *(const int4*)(gp + idx);
  float4 x  = *(const float4*)(e0p + idx);
  float4 y  = *(const float4*)(e1p + idx);
  float4 sg = *(const float4*)(sp + idx);
#define ACC(L, X, Y, SG)                                              \
  if (L > 0) {                                                        \
    atomicAdd(&a0[w][L], X); atomicAdd(&a1[w][L], Y);                 \
    atomicAdd(&as_[w][L], SG); atomicAdd(&as2[w][L], (SG) * (SG));    \
    atomicAdd(&ac[w][L], 1u);                                         \
  }
  ACC(lb.x, x.x, y.x, sg.x)
  ACC(lb.y, x.y, y.y, sg.y)
  ACC(lb.z, x.z, y.z, sg.z)
  ACC(lb.w, x.w, y.w, sg.w)
#undef ACC
  __syncthreads();
  if (t >= 1 && t < NC) {
    float s0 = a0[0][t] + a0[1][t] + a0[2][t] + a0[3][t];
    float s1 = a1[0][t] + a1[1][t] + a1[2][t] + a1[3][t];
    float ss = as_[0][t] + as_[1][t] + as_[2][t] + as_[3][t];
    float s2 = as2[0][t] + as2[1][t] + as2[2][t] + as2[3][t];
    unsigned c = ac[0][t] + ac[1][t] + ac[2][t] + ac[3][t];
    if (c) {
      atomicAdd(&wsS[W_E0 + t], s0);
      atomicAdd(&wsS[W_E1 + t], s1);
      atomicAdd(&wsS[W_SS + t], ss);
      atomicAdd(&wsS[W_SS2 + t], s2);
      atomicAdd((unsigned*)wsS + (W_CNT + t), c);
    }
  }
}

// ---------------- Pass B: t-space histogram, FMA-form bin calc, 4 px/thread
// bin_f = Q'*|p|^2 + A'*px + B'*py + D'  (all pre-scaled by BSCALE)
__global__ void __launch_bounds__(512) hist_kernel(
    const float* __restrict__ emb, const int* __restrict__ gt,
    float* __restrict__ ws) {
  int s = blockIdx.y;
  float* wsS = ws + (size_t)s * W_STRIDE;
  __shared__ unsigned hist[NB * 4];
  __shared__ float4 cons[NC];
  int t = threadIdx.x;
  int r = t & 3;
  for (int k = t; k < NB * 4; k += 512) hist[k] = 0u;
  if (t >= 1 && t < NC) {
    float inv = 1.0f / (float)((const unsigned*)wsS)[W_CNT + t];
    float c0 = wsS[W_E0 + t] * inv;
    float c1 = wsS[W_E1 + t] * inv;
    float sgm = wsS[W_SS + t] * inv;
    float Q = 0.5f / (sgm * sgm) * BSCALE;
    float4 c;
    c.x = Q;                          // * |p|^2
    c.y = -2.0f * Q * c0;             // * px
    c.z = -2.0f * Q * c1;             // * py
    c.w = Q * (c0 * c0 + c1 * c1);    // const
    cons[t] = c;
  }
  __syncthreads();
  const float* e0p = emb + (size_t)s * 2 * HW;
  const float* e1p = e0p + HW;
  const int*   gp  = gt  + (size_t)s * HW;
  int idx = blockIdx.x * 2048 + t * 4;
  int4   lb = *(const int4*)(gp + idx);
  float4 px = *(const float4*)(e0p + idx);
  float4 py = *(const float4*)(e1p + idx);
  float4 ss;
  ss.x = fmaf(px.x, px.x, py.x * py.x);
  ss.y = fmaf(px.y, px.y, py.y * py.y);
  ss.z = fmaf(px.z, px.z, py.z * py.z);
  ss.w = fmaf(px.w, px.w, py.w * py.w);
  unsigned* hr = hist + r;
  #pragma unroll 4
  for (int n = 1; n <= NI; ++n) {
    float4 C = cons[n];
#define ITEM(P0, P1, SV, L)                                            \
    {                                                                  \
      float bf = fmaf(C.x, SV, fmaf(C.y, P0, fmaf(C.z, P1, C.w)));     \
      int ib = (int)bf;                                                \
      bool pos = (L == n);                                             \
      if (pos) ib = min(ib, NB - 1);                                   \
      if (ib < NB) atomicAdd(&hr[ib << 2], pos ? 0x10000u : 1u);       \
    }
    ITEM(px.x, py.x, ss.x, lb.x)
    ITEM(px.y, py.y, ss.y, lb.y)
    ITEM(px.z, py.z, ss.z, lb.z)
    ITEM(px.w, py.w, ss.w, lb.w)
#undef ITEM
  }
  __syncthreads();
  // flush: one u64 atomic per nonzero bin
  ull* th = (ull*)wsS;  // W_TH == 0
  for (int k = t; k < NB; k += 512) {
    unsigned v = hist[k * 4] + hist[k * 4 + 1] + hist[k * 4 + 2] + hist[k * 4 + 3];
    if (v) {
      ull add = ((ull)(v >> 16) << 32) | (v & 0xFFFFu);
      atomicAdd(&th[k], add);
    }
  }
}

// ---------------- Pass C: single block, loops 4 samples; resample + parallel
// descending Jaccard scan; writes final mean.
__global__ void __launch_bounds__(512) scan_final_kernel(
    float* __restrict__ ws, float* __restrict__ out) {
  __shared__ unsigned ep[EG], en[EG];
  __shared__ ull wsum[8];
  __shared__ float red[8];
  __shared__ float vart_s;
  int t = threadIdx.x;
  int lane = t & 63, wid = t >> 6;
  float acc = 0.f;   // only thread 0's copy matters
  for (int s = 0; s < BNUM; ++s) {
    float* wsS = ws + (size_t)s * W_STRIDE;
    const ull* th = (const ull*)wsS;
    const unsigned* wsu = (const unsigned*)wsS;
    for (int k = t; k < EG; k += 512) { ep[k] = 0u; en[k] = 0u; }
    // pooled variance term: vart = S_total * (sum_n 1/c_n) / NI
    if (wid == 0) {
      float S = 0.f, rc = 0.f;
      if (lane >= 1 && lane < NC) {
        float c = (float)wsu[W_CNT + lane];
        float sg = wsS[W_SS + lane] / c;
        S = wsS[W_SS2 + lane] - c * sg * sg;
        rc = 1.0f / c;
      }
      for (int o = 32; o; o >>= 1) {
        S  += __shfl_down(S, o);
        rc += __shfl_down(rc, o);
      }
      if (lane == 0) vart_s = S * rc / (float)NI;
    }
    __syncthreads();
    // scatter t-bins onto e-grid
    for (int b = t; b < NB; b += 512) {
      ull v = th[b];
      unsigned pos = (unsigned)(v >> 32), neg = (unsigned)(v & 0xFFFFFFFFu);
      if (pos | neg) {
        float tc = ((float)b + 0.5f) * (1.0f / BSCALE);
        float ex = __expf(-tc);
        if (pos) {
          float e = 2.0f - 2.0f * ex;
          int k = (int)(e * ESCALE); if (k > EG - 1) k = EG - 1;
          atomicAdd(&ep[k], pos);
        }
        if (neg) {
          float e = 2.0f * ex;
          int k = (int)(e * ESCALE); if (k > EG - 1) k = EG - 1;
          atomicAdd(&en[k], neg);
        }
      }
    }
    __syncthreads();
    // per-thread chunk sums over descending-e order
    const int CH = EG / 512;  // 16
    int j0 = t * CH;
    unsigned np = 0, nn = 0;
    for (int k = 0; k < CH; ++k) {
      int b = EG - 1 - (j0 + k);
      np += ep[b]; nn += en[b];
    }
    // parallel exclusive scan of packed (np<<32)|nn across 512 threads
    ull v = ((ull)np << 32) | (ull)nn;
    ull inc = v;
    for (int o = 1; o < 64; o <<= 1) {
      ull u = __shfl_up(inc, o);
      if (lane >= o) inc += u;
    }
    if (lane == 63) wsum[wid] = inc;
    __syncthreads();
    ull offset = 0, total = 0;
    for (int i = 0; i < 8; ++i) {
      ull x = wsum[i];
      if (i < wid) offset += x;
      total += x;
    }
    ull excl = offset + inc - v;
    float P = (float)(unsigned)(total >> 32);
    unsigned p = (unsigned)(excl >> 32), f = (unsigned)(excl & 0xFFFFFFFFu);
    float jprev = 1.0f - (P - (float)p) / (P + (float)f);
    float contrib = 0.f;
    for (int k = 0; k < CH; ++k) {
      int b = EG - 1 - (j0 + k);
      unsigned ap_ = ep[b], an_ = en[b];
      if (ap_ | an_) {
        p += ap_; f += an_;
        float j = 1.0f - (P - (float)p) / (P + (float)f);
        float e = ((float)b + 0.5f) * (2.0f / EG);
        contrib += e * (j - jprev);
        jprev = j;
      }
    }
    for (int o = 32; o; o >>= 1) contrib += __shfl_down(contrib, o);
    if (lane == 0) red[wid] = contrib;
    __syncthreads();
    if (t == 0) {
      float tot = 0.f;
      for (int i = 0; i < 8; ++i) tot += red[i];
      acc += tot + vart_s;
    }
    __syncthreads();  // protect ep/en/red/vart_s before next sample
  }
  if (t == 0) out[0] = acc * (1.0f / BNUM);
}

extern "C" void kernel_launch(void* const* d_in, const int* in_sizes, int n_in,
                              void* d_out, int out_size, void* d_ws, size_t ws_size,
                              hipStream_t stream) {
  const float* emb = (const float*)d_in[0];   // [4,2,512,512]
  const float* sig = (const float*)d_in[1];   // [4,1,512,512]
  const int*   gt  = (const int*)d_in[2];     // [4,1,512,512]
  float* out = (float*)d_out;
  float* ws  = (float*)d_ws;

  hipMemsetAsync(d_ws, 0, (size_t)BNUM * W_STRIDE * sizeof(float), stream);

  dim3 gA(256, BNUM);
  stats_kernel<<<gA, 256, 0, stream>>>(emb, sig, gt, ws);
  dim3 gB(128, BNUM);
  hist_kernel<<<gB, 512, 0, stream>>>(emb, gt, ws);
  scan_final_kernel<<<1, 512, 0, stream>>>(ws, out);
}

// Round 6
// 126.035 us; speedup vs baseline: 1.1847x; 1.1847x over previous
//
#include <hip/hip_runtime.h>

#define HW    262144      // 512*512
#define BNUM  4
#define NC    33          // labels 0..32
#define NI    32          // instance channels

#define NB     2048       // t-space bins
#define BSCALE 128.0f     // NB / TMAX (TMAX = 16)
#define EG     8192       // e-grid bins in scan
#define ESCALE 4096.0f    // EG / 2.0

typedef unsigned long long ull;

// word (float/u32) offsets within each sample's workspace slice
#define W_TH   0                    // u64[NB] packed (pos<<32)|neg -> 4096 words
#define W_E0   4096
#define W_E1   (W_E0 + NC)          // 4129
#define W_SS   (W_E1 + NC)          // 4162
#define W_SS2  (W_SS + NC)          // 4195
#define W_CNT  (W_SS2 + NC)         // 4228
#define W_STRIDE 4262               // even stride, 16B-aligned base ok
// finalize region (after all samples): 4 loss slots + counter
#define W_FIN  (BNUM * W_STRIDE)    // floats [W_FIN..W_FIN+3], counter u32 at W_FIN+4
#define WS_ZERO_BYTES ((W_FIN + 8) * 4)

// ---------------- Pass A: per-instance stats, per-wave privatized, 4 px/thread
__global__ void __launch_bounds__(256) stats_kernel(
    const float* __restrict__ emb, const float* __restrict__ sig,
    const int* __restrict__ gt, float* __restrict__ ws) {
  int s = blockIdx.y;
  float* wsS = ws + (size_t)s * W_STRIDE;
  __shared__ float a0[4][NC], a1[4][NC], as_[4][NC], as2[4][NC];
  __shared__ unsigned ac[4][NC];
  int t = threadIdx.x;
  int w = t >> 6;
  for (int k = t; k < 4 * NC; k += 256) {
    ((float*)a0)[k] = 0.f; ((float*)a1)[k] = 0.f;
    ((float*)as_)[k] = 0.f; ((float*)as2)[k] = 0.f;
    ((unsigned*)ac)[k] = 0u;
  }
  __syncthreads();
  const float* e0p = emb + (size_t)s * 2 * HW;
  const float* e1p = e0p + HW;
  const float* sp  = sig + (size_t)s * HW;
  const int*   gp  = gt  + (size_t)s * HW;
  int idx = blockIdx.x * 1024 + t * 4;
  int4   lb = *(const int4*)(gp + idx);
  float4 x  = *(const float4*)(e0p + idx);
  float4 y  = *(const float4*)(e1p + idx);
  float4 sg = *(const float4*)(sp + idx);
#define ACC(L, X, Y, SG)                                              \
  if (L > 0) {                                                        \
    atomicAdd(&a0[w][L], X); atomicAdd(&a1[w][L], Y);                 \
    atomicAdd(&as_[w][L], SG); atomicAdd(&as2[w][L], (SG) * (SG));    \
    atomicAdd(&ac[w][L], 1u);                                         \
  }
  ACC(lb.x, x.x, y.x, sg.x)
  ACC(lb.y, x.y, y.y, sg.y)
  ACC(lb.z, x.z, y.z, sg.z)
  ACC(lb.w, x.w, y.w, sg.w)
#undef ACC
  __syncthreads();
  if (t >= 1 && t < NC) {
    float s0 = a0[0][t] + a0[1][t] + a0[2][t] + a0[3][t];
    float s1 = a1[0][t] + a1[1][t] + a1[2][t] + a1[3][t];
    float ss = as_[0][t] + as_[1][t] + as_[2][t] + as_[3][t];
    float s2 = as2[0][t] + as2[1][t] + as2[2][t] + as2[3][t];
    unsigned c = ac[0][t] + ac[1][t] + ac[2][t] + ac[3][t];
    if (c) {
      atomicAdd(&wsS[W_E0 + t], s0);
      atomicAdd(&wsS[W_E1 + t], s1);
      atomicAdd(&wsS[W_SS + t], ss);
      atomicAdd(&wsS[W_SS2 + t], s2);
      atomicAdd((unsigned*)wsS + (W_CNT + t), c);
    }
  }
}

// ---------------- Pass B: t-space histogram, FMA-form bin calc, 4 px/thread
// bin_f = Q'*|p|^2 + A'*px + B'*py + D'  (all pre-scaled by BSCALE)
__global__ void __launch_bounds__(512) hist_kernel(
    const float* __restrict__ emb, const int* __restrict__ gt,
    float* __restrict__ ws) {
  int s = blockIdx.y;
  float* wsS = ws + (size_t)s * W_STRIDE;
  __shared__ unsigned hist[NB * 4];
  __shared__ float4 cons[NC];
  int t = threadIdx.x;
  int r = t & 3;
  for (int k = t; k < NB * 4; k += 512) hist[k] = 0u;
  if (t >= 1 && t < NC) {
    float inv = 1.0f / (float)((const unsigned*)wsS)[W_CNT + t];
    float c0 = wsS[W_E0 + t] * inv;
    float c1 = wsS[W_E1 + t] * inv;
    float sgm = wsS[W_SS + t] * inv;
    float Q = 0.5f / (sgm * sgm) * BSCALE;
    float4 c;
    c.x = Q;                          // * |p|^2
    c.y = -2.0f * Q * c0;             // * px
    c.z = -2.0f * Q * c1;             // * py
    c.w = Q * (c0 * c0 + c1 * c1);    // const
    cons[t] = c;
  }
  __syncthreads();
  const float* e0p = emb + (size_t)s * 2 * HW;
  const float* e1p = e0p + HW;
  const int*   gp  = gt  + (size_t)s * HW;
  int idx = blockIdx.x * 2048 + t * 4;
  int4   lb = *(const int4*)(gp + idx);
  float4 px = *(const float4*)(e0p + idx);
  float4 py = *(const float4*)(e1p + idx);
  float4 ss;
  ss.x = fmaf(px.x, px.x, py.x * py.x);
  ss.y = fmaf(px.y, px.y, py.y * py.y);
  ss.z = fmaf(px.z, px.z, py.z * py.z);
  ss.w = fmaf(px.w, px.w, py.w * py.w);
  unsigned* hr = hist + r;
  #pragma unroll 4
  for (int n = 1; n <= NI; ++n) {
    float4 C = cons[n];
#define ITEM(P0, P1, SV, L)                                            \
    {                                                                  \
      float bf = fmaf(C.x, SV, fmaf(C.y, P0, fmaf(C.z, P1, C.w)));     \
      int ib = (int)bf;                                                \
      bool pos = (L == n);                                             \
      if (pos) ib = min(ib, NB - 1);                                   \
      if (ib < NB) atomicAdd(&hr[ib << 2], pos ? 0x10000u : 1u);       \
    }
    ITEM(px.x, py.x, ss.x, lb.x)
    ITEM(px.y, py.y, ss.y, lb.y)
    ITEM(px.z, py.z, ss.z, lb.z)
    ITEM(px.w, py.w, ss.w, lb.w)
#undef ITEM
  }
  __syncthreads();
  // flush: one u64 atomic per nonzero bin
  ull* th = (ull*)wsS;  // W_TH == 0
  for (int k = t; k < NB; k += 512) {
    unsigned v = hist[k * 4] + hist[k * 4 + 1] + hist[k * 4 + 2] + hist[k * 4 + 3];
    if (v) {
      ull add = ((ull)(v >> 16) << 32) | (v & 0xFFFFu);
      atomicAdd(&th[k], add);
    }
  }
}

// ---------------- Pass C: 4 blocks (one per sample); resample + parallel
// descending Jaccard scan; last-arriving block finalizes out[0].
__global__ void __launch_bounds__(512) scan_kernel(
    float* __restrict__ ws, float* __restrict__ out) {
  int s = blockIdx.x;
  float* wsS = ws + (size_t)s * W_STRIDE;
  const ull* th = (const ull*)wsS;
  const unsigned* wsu = (const unsigned*)wsS;
  __shared__ unsigned ep[EG], en[EG];
  __shared__ ull wsum[8];
  __shared__ float red[8];
  __shared__ float vart_s;
  int t = threadIdx.x;
  int lane = t & 63, wid = t >> 6;
  for (int k = t; k < EG; k += 512) { ep[k] = 0u; en[k] = 0u; }
  // pooled variance term: vart = S_total * (sum_n 1/c_n) / NI
  if (wid == 0) {
    float S = 0.f, rc = 0.f;
    if (lane >= 1 && lane < NC) {
      float c = (float)wsu[W_CNT + lane];
      float sg = wsS[W_SS + lane] / c;
      S = wsS[W_SS2 + lane] - c * sg * sg;
      rc = 1.0f / c;
    }
    for (int o = 32; o; o >>= 1) {
      S  += __shfl_down(S, o);
      rc += __shfl_down(rc, o);
    }
    if (lane == 0) vart_s = S * rc / (float)NI;
  }
  __syncthreads();
  // scatter t-bins onto e-grid
  for (int b = t; b < NB; b += 512) {
    ull v = th[b];
    unsigned pos = (unsigned)(v >> 32), neg = (unsigned)(v & 0xFFFFFFFFu);
    if (pos | neg) {
      float tc = ((float)b + 0.5f) * (1.0f / BSCALE);
      float ex = __expf(-tc);
      if (pos) {
        float e = 2.0f - 2.0f * ex;
        int k = (int)(e * ESCALE); if (k > EG - 1) k = EG - 1;
        atomicAdd(&ep[k], pos);
      }
      if (neg) {
        float e = 2.0f * ex;
        int k = (int)(e * ESCALE); if (k > EG - 1) k = EG - 1;
        atomicAdd(&en[k], neg);
      }
    }
  }
  __syncthreads();
  // per-thread chunk sums over descending-e order
  const int CH = EG / 512;  // 16
  int j0 = t * CH;
  unsigned np = 0, nn = 0;
  for (int k = 0; k < CH; ++k) {
    int b = EG - 1 - (j0 + k);
    np += ep[b]; nn += en[b];
  }
  // parallel exclusive scan of packed (np<<32)|nn across 512 threads
  ull v = ((ull)np << 32) | (ull)nn;
  ull inc = v;
  for (int o = 1; o < 64; o <<= 1) {
    ull u = __shfl_up(inc, o);
    if (lane >= o) inc += u;
  }
  if (lane == 63) wsum[wid] = inc;
  __syncthreads();
  ull offset = 0, total = 0;
  for (int i = 0; i < 8; ++i) {
    ull x = wsum[i];
    if (i < wid) offset += x;
    total += x;
  }
  ull excl = offset + inc - v;
  float P = (float)(unsigned)(total >> 32);
  unsigned p = (unsigned)(excl >> 32), f = (unsigned)(excl & 0xFFFFFFFFu);
  float jprev = 1.0f - (P - (float)p) / (P + (float)f);
  float contrib = 0.f;
  for (int k = 0; k < CH; ++k) {
    int b = EG - 1 - (j0 + k);
    unsigned ap_ = ep[b], an_ = en[b];
    if (ap_ | an_) {
      p += ap_; f += an_;
      float j = 1.0f - (P - (float)p) / (P + (float)f);
      float e = ((float)b + 0.5f) * (2.0f / EG);
      contrib += e * (j - jprev);
      jprev = j;
    }
  }
  for (int o = 32; o; o >>= 1) contrib += __shfl_down(contrib, o);
  if (lane == 0) red[wid] = contrib;
  __syncthreads();
  if (t == 0) {
    float tot = 0.f;
    for (int i = 0; i < 8; ++i) tot += red[i];
    float loss = tot + vart_s;
    // publish loss (device-scope atomic store), then bump counter
    float* fin = ws + W_FIN;
    unsigned* cnt = (unsigned*)(fin + 4);
    atomicExch(&fin[s], loss);
    unsigned old = atomicAdd(cnt, 1u);
    if (old == BNUM - 1) {
      float a = 0.f;
      for (int i = 0; i < BNUM; ++i) a += atomicAdd(&fin[i], 0.0f);
      out[0] = a * (1.0f / BNUM);
    }
  }
}

extern "C" void kernel_launch(void* const* d_in, const int* in_sizes, int n_in,
                              void* d_out, int out_size, void* d_ws, size_t ws_size,
                              hipStream_t stream) {
  const float* emb = (const float*)d_in[0];   // [4,2,512,512]
  const float* sig = (const float*)d_in[1];   // [4,1,512,512]
  const int*   gt  = (const int*)d_in[2];     // [4,1,512,512]
  float* out = (float*)d_out;
  float* ws  = (float*)d_ws;

  hipMemsetAsync(d_ws, 0, WS_ZERO_BYTES, stream);

  dim3 gA(256, BNUM);
  stats_kernel<<<gA, 256, 0, stream>>>(emb, sig, gt, ws);
  dim3 gB(128, BNUM);
  hist_kernel<<<gB, 512, 0, stream>>>(emb, gt, ws);
  scan_kernel<<<BNUM, 512, 0, stream>>>(ws, out);
}